// Round 13
// baseline (4824.817 us; speedup 1.0000x reference)
//
#include <hip/hip_runtime.h>

#define B_DIM 64
#define T_DIM 2048
#define F_DIM 512
#define H_DIM 128
#define G_DIM 384  // 3*H

typedef _Float16 half2_t __attribute__((ext_vector_type(2)));
typedef unsigned int uint32;
typedef short bf16x8 __attribute__((ext_vector_type(8)));
typedef float f32x4  __attribute__((ext_vector_type(4)));

__device__ __forceinline__ float sigmoid_f(float x) {
    return __fdividef(1.0f, 1.0f + __expf(-x));
}
__device__ __forceinline__ float tanh_f(float x) {
    return __fdividef(2.0f, 1.0f + __expf(-2.0f * x)) - 1.0f;
}

__device__ __forceinline__ uint32 packf16(float a, float b) {
    half2_t p; p.x = (_Float16)a; p.y = (_Float16)b;
    return __builtin_bit_cast(uint32, p);
}

__device__ __forceinline__ float dot2(uint32 w, uint32 h, float acc) {
#if __has_builtin(__builtin_amdgcn_fdot2)
    return __builtin_amdgcn_fdot2(__builtin_bit_cast(half2_t, w),
                                  __builtin_bit_cast(half2_t, h), acc, false);
#else
    half2_t a = __builtin_bit_cast(half2_t, w), b2 = __builtin_bit_cast(half2_t, h);
    acc = fmaf((float)a.x, (float)b2.x, acc);
    return fmaf((float)a.y, (float)b2.y, acc);
#endif
}

__device__ __forceinline__ uint32 pk_bf16(float lo, float hi) {
    uint32 r;
    asm("v_cvt_pk_bf16_f32 %0, %1, %2" : "=v"(r) : "v"(lo), "v"(hi));
    return r;
}

#define DPP_QUAD_ADD(var, CTRL)                                                   \
    { int _t = __builtin_amdgcn_mov_dpp(__builtin_bit_cast(int, var),             \
                                        CTRL, 0xF, 0xF, true);                    \
      var += __builtin_bit_cast(float, _t); }

// ---------------------------------------------------------------------------
// bf16 MFMA GEMM (R10-proven): C[M x NDIM] = A @ W^T + bias; optional lengths.
// ---------------------------------------------------------------------------
template<int KDIM, int NDIM, bool DO_LEN>
__global__ __launch_bounds__(256)
void gemm_mfma_kernel(const float* __restrict__ A, const float* __restrict__ W,
                      const float* __restrict__ bias, float* __restrict__ C,
                      int* __restrict__ lengths)
{
    constexpr int KSTEPS = KDIM / 32;
    constexpr int PAD = 40;
    __shared__ __align__(16) unsigned short At[128 * PAD];
    __shared__ __align__(16) unsigned short Bt[128 * PAD];

    const int tid = threadIdx.x;
    const int m0  = blockIdx.x * 128;
    const int n0  = blockIdx.y * 128;
    const int row = tid >> 1;
    const int kh  = tid & 1;

    const float* Ap = A + (size_t)(m0 + row) * KDIM + kh * 16;
    const float* Wp = W + (size_t)(n0 + row) * KDIM + kh * 16;

    float4 aPre[4], bPre[4];
#pragma unroll
    for (int q = 0; q < 4; ++q) {
        aPre[q] = *(const float4*)(Ap + q * 4);
        bPre[q] = *(const float4*)(Wp + q * 4);
    }

    f32x4 acc[4][4];
#pragma unroll
    for (int i = 0; i < 4; ++i)
#pragma unroll
        for (int j = 0; j < 4; ++j) acc[i][j] = (f32x4){0.f, 0.f, 0.f, 0.f};

    const int wv = tid >> 6;
    const int wm = (wv >> 1) * 64;
    const int wn = (wv & 1) * 64;
    const int ln = tid & 63;
    const int fr = ln & 15;
    const int fq = ln >> 4;

    float rowsum = 0.0f;

    for (int ks = 0; ks < KSTEPS; ++ks) {
        if (DO_LEN) {
#pragma unroll
            for (int q = 0; q < 4; ++q)
                rowsum += aPre[q].x + aPre[q].y + aPre[q].z + aPre[q].w;
        }
        {
            uint32* ad = (uint32*)&At[row * PAD + kh * 16];
            uint32* bd = (uint32*)&Bt[row * PAD + kh * 16];
            uint4 au, bu;
            au.x = pk_bf16(aPre[0].x, aPre[0].y); au.y = pk_bf16(aPre[0].z, aPre[0].w);
            au.z = pk_bf16(aPre[1].x, aPre[1].y); au.w = pk_bf16(aPre[1].z, aPre[1].w);
            *(uint4*)ad = au;
            au.x = pk_bf16(aPre[2].x, aPre[2].y); au.y = pk_bf16(aPre[2].z, aPre[2].w);
            au.z = pk_bf16(aPre[3].x, aPre[3].y); au.w = pk_bf16(aPre[3].z, aPre[3].w);
            *(uint4*)(ad + 4) = au;
            bu.x = pk_bf16(bPre[0].x, bPre[0].y); bu.y = pk_bf16(bPre[0].z, bPre[0].w);
            bu.z = pk_bf16(bPre[1].x, bPre[1].y); bu.w = pk_bf16(bPre[1].z, bPre[1].w);
            *(uint4*)bd = bu;
            bu.x = pk_bf16(bPre[2].x, bPre[2].y); bu.y = pk_bf16(bPre[2].z, bPre[2].w);
            bu.z = pk_bf16(bPre[3].x, bPre[3].y); bu.w = pk_bf16(bPre[3].z, bPre[3].w);
            *(uint4*)(bd + 4) = bu;
        }
        __syncthreads();
        if (ks + 1 < KSTEPS) {
#pragma unroll
            for (int q = 0; q < 4; ++q) {
                aPre[q] = *(const float4*)(Ap + (ks + 1) * 32 + q * 4);
                bPre[q] = *(const float4*)(Wp + (ks + 1) * 32 + q * 4);
            }
        }
        bf16x8 aF[4], bF[4];
#pragma unroll
        for (int i = 0; i < 4; ++i) {
            aF[i] = *(const bf16x8*)&At[(wm + i * 16 + fr) * PAD + fq * 8];
            bF[i] = *(const bf16x8*)&Bt[(wn + i * 16 + fr) * PAD + fq * 8];
        }
#pragma unroll
        for (int i = 0; i < 4; ++i)
#pragma unroll
            for (int j = 0; j < 4; ++j)
                acc[i][j] = __builtin_amdgcn_mfma_f32_16x16x32_bf16(
                                aF[i], bF[j], acc[i][j], 0, 0, 0);
        __syncthreads();
    }

#pragma unroll
    for (int i = 0; i < 4; ++i) {
#pragma unroll
        for (int j = 0; j < 4; ++j) {
            const int n = n0 + wn + j * 16 + fr;
            const float bn = bias[n];
            const int mbase = m0 + wm + i * 16 + fq * 4;
#pragma unroll
            for (int r = 0; r < 4; ++r)
                C[(size_t)(mbase + r) * NDIM + n] = acc[i][j][r] + bn;
        }
    }

    if (DO_LEN && blockIdx.y == 0) {
        rowsum += __shfl_xor(rowsum, 1);
        if (kh == 0 && rowsum != 0.0f)
            atomicAdd(&lengths[(m0 + row) >> 11], 1);
    }
}

// Pack w_ih[1] (fp32 [3H][H]) -> f16x2 u32 buffer, same row layout:
// dst[row*64 + c] = pack(src[row*128 + 2c], src[row*128 + 2c+1])
__global__ __launch_bounds__(256)
void pack_wih1_kernel(const float* __restrict__ src, uint32* __restrict__ dst)
{
    int gid = blockIdx.x * 256 + threadIdx.x;   // 0..24575
    int row = gid >> 6;
    int c   = gid & 63;
    dst[gid] = packf16(src[row * 128 + 2 * c], src[row * 128 + 2 * c + 1]);
}

// ---------------------------------------------------------------------------
// FUSED two-layer GRU scan, 1024 threads (16 waves), one block per batch elem.
//   tid<512  (L0): R9-exact — jj=tid>>2, kq=tid&3; 48 resident u32 of w_hh0;
//            reads gx (2-ahead ping-pong), h0 from LDS; writes h0 + out0 f16.
//   tid>=512 (L1): same (jj,kq); 48 resident u32 of w_hh1; w_ih1 STREAMED
//            per step from pre-packed f16 global (gate-by-gate, 4 dwordx4
//            each, coalesced); reads out0[t-1] + h1[t-2] from LDS.
// L1 lags L0 by one step; out0 passes via LDS only. ONE barrier per step.
// Both roles stay <=48 resident u32: the R4-R11-established allocator
// comfort ceiling (96 -> remat, 2x step cost).
// ---------------------------------------------------------------------------
#define HPU 76   // replica pitch in u32 (bank shift 12)

#define FUSED_STEP(PR, CXR, CXZ, CXN)                                             \
    {                                                                             \
        if (tid < 512) {                                                          \
            if (t < len) {                                                        \
                const uint32* hbp = &h0_rep[PR][kq * HPU + kq * 16];              \
                uint4 v0 = *(const uint4*)(hbp + 0);                              \
                uint4 v1 = *(const uint4*)(hbp + 4);                              \
                uint4 v2 = *(const uint4*)(hbp + 8);                              \
                uint4 v3 = *(const uint4*)(hbp + 12);                             \
                uint32 hu[16] = {v0.x,v0.y,v0.z,v0.w, v1.x,v1.y,v1.z,v1.w,        \
                                 v2.x,v2.y,v2.z,v2.w, v3.x,v3.y,v3.z,v3.w};       \
                float ar = 0.f, az = 0.f, an = 0.f;                               \
                _Pragma("unroll")                                                 \
                for (int i = 0; i < 16; ++i) {                                    \
                    ar = dot2(uA[i], hu[i], ar);                                  \
                    az = dot2(uB[i], hu[i], az);                                  \
                    an = dot2(uC[i], hu[i], an);                                  \
                }                                                                 \
                DPP_QUAD_ADD(ar, 0xB1); DPP_QUAD_ADD(az, 0xB1);                   \
                DPP_QUAD_ADD(an, 0xB1);                                           \
                DPP_QUAD_ADD(ar, 0x4E); DPP_QUAD_ADD(az, 0x4E);                   \
                DPP_QUAD_ADD(an, 0x4E);                                           \
                int tp = t + 2; if (tp > T_DIM - 1) tp = T_DIM - 1;               \
                const float* gp = gxb + (size_t)tp * G_DIM + jj;                  \
                float nxr = gp[0], nxz = gp[128], nxn = gp[256];                  \
                float r  = sigmoid_f(CXR + ar + br);                              \
                float z  = sigmoid_f(CXZ + az + bz);                              \
                float nn = tanh_f(CXN + r * (an + bnH));                          \
                float hnew = nn + z * (h_prev - nn);                              \
                h_prev = hnew;                                                    \
                _Float16 h16 = (_Float16)hnew;                                    \
                ((_Float16*)&h0_rep[PR ^ 1][kq * HPU])[jj] = h16;                 \
                ((_Float16*)&o0_rep[PR ^ 1][kq * HPU])[jj] = h16;                 \
                CXR = nxr; CXZ = nxz; CXN = nxn;                                  \
            }                                                                     \
        } else {                                                                  \
            if (t >= 1) {                                                         \
                const uint32* obp = &o0_rep[PR][kq * HPU + kq * 16];              \
                const uint32* hbp = &h1_rep[PR][kq * HPU + kq * 16];              \
                uint4 o0v = *(const uint4*)(obp + 0);                             \
                uint4 o1v = *(const uint4*)(obp + 4);                             \
                uint4 o2v = *(const uint4*)(obp + 8);                             \
                uint4 o3v = *(const uint4*)(obp + 12);                            \
                uint4 h0v = *(const uint4*)(hbp + 0);                             \
                uint4 h1v = *(const uint4*)(hbp + 4);                             \
                uint4 h2v = *(const uint4*)(hbp + 8);                             \
                uint4 h3v = *(const uint4*)(hbp + 12);                            \
                uint32 ou[16] = {o0v.x,o0v.y,o0v.z,o0v.w, o1v.x,o1v.y,o1v.z,o1v.w,\
                                 o2v.x,o2v.y,o2v.z,o2v.w, o3v.x,o3v.y,o3v.z,o3v.w};\
                uint32 hu[16] = {h0v.x,h0v.y,h0v.z,h0v.w, h1v.x,h1v.y,h1v.z,h1v.w,\
                                 h2v.x,h2v.y,h2v.z,h2v.w, h3v.x,h3v.y,h3v.z,h3v.w};\
                float ahr = 0.f, ahz = 0.f, ahn = 0.f;                            \
                _Pragma("unroll")                                                 \
                for (int i = 0; i < 16; ++i) {                                    \
                    ahr = dot2(uA[i], hu[i], ahr);                                \
                    ahz = dot2(uB[i], hu[i], ahz);                                \
                    ahn = dot2(uC[i], hu[i], ahn);                                \
                }                                                                 \
                float air = 0.f, aiz = 0.f, ain = 0.f;                            \
                {   /* gate-by-gate f16 streaming: 16 u32 in flight at a time */  \
                    uint4 w0 = *(const uint4*)(ihp + 0);                          \
                    uint4 w1 = *(const uint4*)(ihp + 4);                          \
                    uint4 w2 = *(const uint4*)(ihp + 8);                          \
                    uint4 w3 = *(const uint4*)(ihp + 12);                         \
                    uint32 wv[16] = {w0.x,w0.y,w0.z,w0.w, w1.x,w1.y,w1.z,w1.w,    \
                                     w2.x,w2.y,w2.z,w2.w, w3.x,w3.y,w3.z,w3.w};   \
                    _Pragma("unroll")                                             \
                    for (int i = 0; i < 16; ++i) air = dot2(wv[i], ou[i], air);   \
                    w0 = *(const uint4*)(ihp + 8192);                             \
                    w1 = *(const uint4*)(ihp + 8196);                             \
                    w2 = *(const uint4*)(ihp + 8200);                             \
                    w3 = *(const uint4*)(ihp + 8204);                             \
                    uint32 wz2[16] = {w0.x,w0.y,w0.z,w0.w, w1.x,w1.y,w1.z,w1.w,   \
                                      w2.x,w2.y,w2.z,w2.w, w3.x,w3.y,w3.z,w3.w};  \
                    _Pragma("unroll")                                             \
                    for (int i = 0; i < 16; ++i) aiz = dot2(wz2[i], ou[i], aiz);  \
                    w0 = *(const uint4*)(ihp + 16384);                            \
                    w1 = *(const uint4*)(ihp + 16388);                            \
                    w2 = *(const uint4*)(ihp + 16392);                            \
                    w3 = *(const uint4*)(ihp + 16396);                            \
                    uint32 wn2[16] = {w0.x,w0.y,w0.z,w0.w, w1.x,w1.y,w1.z,w1.w,   \
                                      w2.x,w2.y,w2.z,w2.w, w3.x,w3.y,w3.z,w3.w};  \
                    _Pragma("unroll")                                             \
                    for (int i = 0; i < 16; ++i) ain = dot2(wn2[i], ou[i], ain);  \
                }                                                                 \
                DPP_QUAD_ADD(ahr, 0xB1); DPP_QUAD_ADD(ahz, 0xB1);                 \
                DPP_QUAD_ADD(ahn, 0xB1); DPP_QUAD_ADD(air, 0xB1);                 \
                DPP_QUAD_ADD(aiz, 0xB1); DPP_QUAD_ADD(ain, 0xB1);                 \
                DPP_QUAD_ADD(ahr, 0x4E); DPP_QUAD_ADD(ahz, 0x4E);                 \
                DPP_QUAD_ADD(ahn, 0x4E); DPP_QUAD_ADD(air, 0x4E);                 \
                DPP_QUAD_ADD(aiz, 0x4E); DPP_QUAD_ADD(ain, 0x4E);                 \
                float r  = sigmoid_f(air + ahr + br);                             \
                float z  = sigmoid_f(aiz + ahz + bz);                             \
                float nn = tanh_f(ain + bnI + r * (ahn + bnH));                   \
                float hnew = nn + z * (h_prev - nn);                              \
                h_prev = hnew;                                                    \
                ((_Float16*)&h1_rep[PR ^ 1][kq * HPU])[jj] = (_Float16)hnew;      \
            }                                                                     \
        }                                                                         \
        __syncthreads();                                                          \
    }

__global__ __attribute__((amdgpu_flat_work_group_size(1024, 1024),
                          amdgpu_waves_per_eu(4, 4)))
void gru_fused_kernel(const float* __restrict__ gx,     // [B,T,3H] layer-0 (incl b_ih0)
                      const float* __restrict__ whh,    // [2,3H,H] fp32
                      const uint32* __restrict__ wih1p, // packed f16 w_ih[1], [3H][64] u32
                      const float* __restrict__ bhh,    // [2,3H]
                      const float* __restrict__ bih1,   // b_ih[1] = [3H]
                      const int*   __restrict__ lengths,
                      float* __restrict__ out)          // [B,H]
{
    __shared__ __align__(16) uint32 h0_rep[2][4 * HPU];
    __shared__ __align__(16) uint32 o0_rep[2][4 * HPU];
    __shared__ __align__(16) uint32 h1_rep[2][4 * HPU];

    const int b   = blockIdx.x;
    const int tid = threadIdx.x;
    const int t2  = tid & 511;         // index within role
    const int jj  = t2 >> 2;           // 0..127
    const int kq  = t2 & 3;            // 0..3

    // role-shared resident set: 48 uints (<= allocator comfort ceiling) + biases
    uint32 uA[16], uB[16], uC[16];
    float br, bz, bnI, bnH;

    const float* wsrc = whh + (tid < 512 ? 0 : (size_t)G_DIM * H_DIM);
    {
        const float* wr_ = wsrc + (size_t)jj * H_DIM + kq * 32;
        const float* wz_ = wr_ + 128 * H_DIM;
        const float* wn_ = wr_ + 256 * H_DIM;
#pragma unroll
        for (int i = 0; i < 16; ++i) {
            uA[i] = packf16(wr_[2*i], wr_[2*i+1]);
            uB[i] = packf16(wz_[2*i], wz_[2*i+1]);
            uC[i] = packf16(wn_[2*i], wn_[2*i+1]);
        }
    }
    if (tid < 512) {
        br = bhh[jj]; bz = bhh[jj + 128]; bnI = 0.0f; bnH = bhh[jj + 256];
    } else {
        const float* bhh1 = bhh + G_DIM;
        br  = bhh1[jj] + bih1[jj];
        bz  = bhh1[jj + 128] + bih1[jj + 128];
        bnI = bih1[jj + 256];
        bnH = bhh1[jj + 256];
    }

    // L1 streaming base: gate r at +0, z at +8192 u32, n at +16384 u32
    const uint32* ihp = wih1p + jj * 64 + kq * 16;

    const int len = lengths[b];
    const float* gxb = gx + (size_t)b * T_DIM * G_DIM;

    for (int i = tid; i < 2 * 4 * HPU; i += 1024) {
        ((uint32*)h0_rep)[i] = 0u;
        ((uint32*)o0_rep)[i] = 0u;
        ((uint32*)h1_rep)[i] = 0u;
    }

    // L0 gx ping-pong prefetch (2 steps ahead); L1 lanes leave these at 0
    float exr = 0.f, exz = 0.f, exn = 0.f, oxr = 0.f, oxz = 0.f, oxn = 0.f;
    if (tid < 512) {
        exr = gxb[jj];         exz = gxb[jj + 128];         exn = gxb[jj + 256];
        oxr = gxb[G_DIM + jj]; oxz = gxb[G_DIM + jj + 128]; oxn = gxb[G_DIM + jj + 256];
    }
    __syncthreads();

    float h_prev = 0.0f;   // L0: h0[jj];  L1: h1[jj]

    int t = 0;
    for (;;) {             // iterations t = 0..len inclusive (L1 lags by 1)
        FUSED_STEP(0, exr, exz, exn)
        ++t; if (t > len) break;
        FUSED_STEP(1, oxr, oxz, oxn)
        ++t; if (t > len) break;
    }

    if (tid >= 512 && kq == 0)
        out[(size_t)b * H_DIM + jj] = h_prev;
}

extern "C" void kernel_launch(void* const* d_in, const int* in_sizes, int n_in,
                              void* d_out, int out_size, void* d_ws, size_t ws_size,
                              hipStream_t stream)
{
    (void)in_sizes; (void)n_in; (void)out_size; (void)ws_size;
    const float* x      = (const float*)d_in[0];
    const float* w_proj = (const float*)d_in[1];
    const float* b_proj = (const float*)d_in[2];
    const float* w_ih   = (const float*)d_in[3];
    const float* w_hh   = (const float*)d_in[4];
    const float* b_ih   = (const float*)d_in[5];
    const float* b_hh   = (const float*)d_in[6];
    float* out = (float*)d_out;

    // ws: [0,64MB) feat; [64MB,256MB) gx; [256MB,+256B) lengths; +4KB wih1 packed (96KB)
    char*   ws      = (char*)d_ws;
    float*  feat    = (float*)(ws);
    float*  gxbuf   = (float*)(ws + 67108864ull);
    int*    lengths = (int*)  (ws + 268435456ull);
    uint32* wih1p   = (uint32*)(ws + 268435456ull + 4096ull);

    hipMemsetAsync(lengths, 0, B_DIM * sizeof(int), stream);

    // 0) pack w_ih[1] -> f16x2 (24576 u32)
    pack_wih1_kernel<<<96, 256, 0, stream>>>(w_ih + (size_t)G_DIM * H_DIM, wih1p);
    // 1) feat = x @ w_proj^T + b_proj (+ lengths)   M=131072, N=128, K=512
    gemm_mfma_kernel<F_DIM, H_DIM, true>
        <<<dim3(1024, 1), 256, 0, stream>>>(x, w_proj, b_proj, feat, lengths);
    // 2) gx0 = feat @ w_ih[0]^T + b_ih[0]           N=384, K=128
    gemm_mfma_kernel<H_DIM, G_DIM, false>
        <<<dim3(1024, 3), 256, 0, stream>>>(feat, w_ih, b_ih, gxbuf, nullptr);
    // 3) fused layer-0 + layer-1 scan -> final top-layer state
    gru_fused_kernel<<<B_DIM, 1024, 0, stream>>>(
        gxbuf, w_hh, wih1p, b_hh, b_ih + G_DIM, lengths, out);
}

// Round 15
// 3665.501 us; speedup vs baseline: 1.3163x; 1.3163x over previous
//
#include <hip/hip_runtime.h>

#define B_DIM 64
#define T_DIM 2048
#define F_DIM 512
#define H_DIM 128
#define G_DIM 384  // 3*H

typedef _Float16 half2_t __attribute__((ext_vector_type(2)));
typedef _Float16 f16x8   __attribute__((ext_vector_type(8)));
typedef unsigned int uint32;
typedef uint32 u32x4 __attribute__((ext_vector_type(4)));
typedef short bf16x8 __attribute__((ext_vector_type(8)));
typedef float f32x4  __attribute__((ext_vector_type(4)));

__device__ __forceinline__ float sigmoid_f(float x) {
    return __fdividef(1.0f, 1.0f + __expf(-x));
}
__device__ __forceinline__ float tanh_f(float x) {
    return __fdividef(2.0f, 1.0f + __expf(-2.0f * x)) - 1.0f;
}

__device__ __forceinline__ uint32 packf16(float a, float b) {
    half2_t p; p.x = (_Float16)a; p.y = (_Float16)b;
    return __builtin_bit_cast(uint32, p);
}

__device__ __forceinline__ uint32 pk_bf16(float lo, float hi) {
    uint32 r;
    asm("v_cvt_pk_bf16_f32 %0, %1, %2" : "=v"(r) : "v"(lo), "v"(hi));
    return r;
}

// ---------------------------------------------------------------------------
// bf16 MFMA GEMM (R10-proven): C[M x NDIM] = A @ W^T + bias; optional lengths.
// ---------------------------------------------------------------------------
template<int KDIM, int NDIM, bool DO_LEN>
__global__ __launch_bounds__(256)
void gemm_mfma_kernel(const float* __restrict__ A, const float* __restrict__ W,
                      const float* __restrict__ bias, float* __restrict__ C,
                      int* __restrict__ lengths)
{
    constexpr int KSTEPS = KDIM / 32;
    constexpr int PAD = 40;
    __shared__ __align__(16) unsigned short At[128 * PAD];
    __shared__ __align__(16) unsigned short Bt[128 * PAD];

    const int tid = threadIdx.x;
    const int m0  = blockIdx.x * 128;
    const int n0  = blockIdx.y * 128;
    const int row = tid >> 1;
    const int kh  = tid & 1;

    const float* Ap = A + (size_t)(m0 + row) * KDIM + kh * 16;
    const float* Wp = W + (size_t)(n0 + row) * KDIM + kh * 16;

    float4 aPre[4], bPre[4];
#pragma unroll
    for (int q = 0; q < 4; ++q) {
        aPre[q] = *(const float4*)(Ap + q * 4);
        bPre[q] = *(const float4*)(Wp + q * 4);
    }

    f32x4 acc[4][4];
#pragma unroll
    for (int i = 0; i < 4; ++i)
#pragma unroll
        for (int j = 0; j < 4; ++j) acc[i][j] = (f32x4){0.f, 0.f, 0.f, 0.f};

    const int wv = tid >> 6;
    const int wm = (wv >> 1) * 64;
    const int wn = (wv & 1) * 64;
    const int ln = tid & 63;
    const int fr = ln & 15;
    const int fq = ln >> 4;

    float rowsum = 0.0f;

    for (int ks = 0; ks < KSTEPS; ++ks) {
        if (DO_LEN) {
#pragma unroll
            for (int q = 0; q < 4; ++q)
                rowsum += aPre[q].x + aPre[q].y + aPre[q].z + aPre[q].w;
        }
        {
            uint32* ad = (uint32*)&At[row * PAD + kh * 16];
            uint32* bd = (uint32*)&Bt[row * PAD + kh * 16];
            uint4 au, bu;
            au.x = pk_bf16(aPre[0].x, aPre[0].y); au.y = pk_bf16(aPre[0].z, aPre[0].w);
            au.z = pk_bf16(aPre[1].x, aPre[1].y); au.w = pk_bf16(aPre[1].z, aPre[1].w);
            *(uint4*)ad = au;
            au.x = pk_bf16(aPre[2].x, aPre[2].y); au.y = pk_bf16(aPre[2].z, aPre[2].w);
            au.z = pk_bf16(aPre[3].x, aPre[3].y); au.w = pk_bf16(aPre[3].z, aPre[3].w);
            *(uint4*)(ad + 4) = au;
            bu.x = pk_bf16(bPre[0].x, bPre[0].y); bu.y = pk_bf16(bPre[0].z, bPre[0].w);
            bu.z = pk_bf16(bPre[1].x, bPre[1].y); bu.w = pk_bf16(bPre[1].z, bPre[1].w);
            *(uint4*)bd = bu;
            bu.x = pk_bf16(bPre[2].x, bPre[2].y); bu.y = pk_bf16(bPre[2].z, bPre[2].w);
            bu.z = pk_bf16(bPre[3].x, bPre[3].y); bu.w = pk_bf16(bPre[3].z, bPre[3].w);
            *(uint4*)(bd + 4) = bu;
        }
        __syncthreads();
        if (ks + 1 < KSTEPS) {
#pragma unroll
            for (int q = 0; q < 4; ++q) {
                aPre[q] = *(const float4*)(Ap + (ks + 1) * 32 + q * 4);
                bPre[q] = *(const float4*)(Wp + (ks + 1) * 32 + q * 4);
            }
        }
        bf16x8 aF[4], bF[4];
#pragma unroll
        for (int i = 0; i < 4; ++i) {
            aF[i] = *(const bf16x8*)&At[(wm + i * 16 + fr) * PAD + fq * 8];
            bF[i] = *(const bf16x8*)&Bt[(wn + i * 16 + fr) * PAD + fq * 8];
        }
#pragma unroll
        for (int i = 0; i < 4; ++i)
#pragma unroll
            for (int j = 0; j < 4; ++j)
                acc[i][j] = __builtin_amdgcn_mfma_f32_16x16x32_bf16(
                                aF[i], bF[j], acc[i][j], 0, 0, 0);
        __syncthreads();
    }

#pragma unroll
    for (int i = 0; i < 4; ++i) {
#pragma unroll
        for (int j = 0; j < 4; ++j) {
            const int n = n0 + wn + j * 16 + fr;
            const float bn = bias[n];
            const int mbase = m0 + wm + i * 16 + fq * 4;
#pragma unroll
            for (int r = 0; r < 4; ++r)
                C[(size_t)(mbase + r) * NDIM + n] = acc[i][j][r] + bn;
        }
    }

    if (DO_LEN && blockIdx.y == 0) {
        rowsum += __shfl_xor(rowsum, 1);
        if (kh == 0 && rowsum != 0.0f)
            atomicAdd(&lengths[(m0 + row) >> 11], 1);
    }
}

// ---------------------------------------------------------------------------
// MFMA-matvec GRU scan. One block per batch element, 512 threads = 8 waves,
// waves_per_eu(2,2) -> 128-VGPR budget.
// Wave w: k-chunk kc=(w&3)*32, j-half j0=(w>>2)*192. Resident weights:
// 12 B-fragments of mfma_f32_16x16x32_f16 = 48 u32 (the R8/R9-proven
// resident count). Per step:
//   A-frag = h[kc + fq*8 .. +8) f16 from LDS (1 ds_read_b128, broadcast) ->
//   12 MFMA (C=0): lane gets a[j0+i*16+(ln&15)] in acc[0] (rows=replica) ->
//   exec-masked partial writes part[kc][j] (16 lanes/tile, conflict-free) ->
//   barrier -> 128 gate threads: 12 part reads + 11 adds + R9 gate math ->
//   h f16 write (double-buffered) + gx 2-ahead prefetch -> barrier.
// Issue/SIMD/step ~250 cyc vs dot2-path's ~720.
// ---------------------------------------------------------------------------
#define PW2 392   // part row pitch (f32)

#define SCAN_STEP(PR, CXR, CXZ, CXN)                                              \
    {                                                                             \
        f16x8 ha = *(const f16x8*)((const _Float16*)&hbuf[PR][0] + kc + fq * 8);  \
        float p0,p1,p2,p3,p4,p5,p6,p7,p8,p9,p10,p11;                              \
        {                                                                         \
            f32x4 z4 = (f32x4){0.f,0.f,0.f,0.f};                                  \
            f32x4 a0 = __builtin_amdgcn_mfma_f32_16x16x32_f16(ha, wF[0], z4,0,0,0);\
            f32x4 a1 = __builtin_amdgcn_mfma_f32_16x16x32_f16(ha, wF[1], z4,0,0,0);\
            f32x4 a2 = __builtin_amdgcn_mfma_f32_16x16x32_f16(ha, wF[2], z4,0,0,0);\
            f32x4 a3 = __builtin_amdgcn_mfma_f32_16x16x32_f16(ha, wF[3], z4,0,0,0);\
            f32x4 a4 = __builtin_amdgcn_mfma_f32_16x16x32_f16(ha, wF[4], z4,0,0,0);\
            f32x4 a5 = __builtin_amdgcn_mfma_f32_16x16x32_f16(ha, wF[5], z4,0,0,0);\
            f32x4 a6 = __builtin_amdgcn_mfma_f32_16x16x32_f16(ha, wF[6], z4,0,0,0);\
            f32x4 a7 = __builtin_amdgcn_mfma_f32_16x16x32_f16(ha, wF[7], z4,0,0,0);\
            f32x4 a8 = __builtin_amdgcn_mfma_f32_16x16x32_f16(ha, wF[8], z4,0,0,0);\
            f32x4 a9 = __builtin_amdgcn_mfma_f32_16x16x32_f16(ha, wF[9], z4,0,0,0);\
            f32x4 aA = __builtin_amdgcn_mfma_f32_16x16x32_f16(ha, wF[10],z4,0,0,0);\
            f32x4 aB = __builtin_amdgcn_mfma_f32_16x16x32_f16(ha, wF[11],z4,0,0,0);\
            p0=a0[0]; p1=a1[0]; p2=a2[0]; p3=a3[0]; p4=a4[0]; p5=a5[0];           \
            p6=a6[0]; p7=a7[0]; p8=a8[0]; p9=a9[0]; p10=aA[0]; p11=aB[0];         \
        }                                                                         \
        {   /* tile i written by lanes with fq == i&3 (16 lanes, consecutive j) */\
            float* pb = &part[kcIdx * PW2 + j0 + fr];                             \
            if (fq == 0) { pb[0]   = p0; pb[64]  = p4; pb[128] = p8;  }           \
            if (fq == 1) { pb[16]  = p1; pb[80]  = p5; pb[144] = p9;  }           \
            if (fq == 2) { pb[32]  = p2; pb[96]  = p6; pb[160] = p10; }           \
            if (fq == 3) { pb[48]  = p3; pb[112] = p7; pb[176] = p11; }           \
        }                                                                         \
        __syncthreads();                                                          \
        if (tid < H_DIM) {                                                        \
            float ar = part[0*PW2 + tid]       + part[1*PW2 + tid]                \
                     + part[2*PW2 + tid]       + part[3*PW2 + tid];               \
            float az = part[0*PW2 + 128 + tid] + part[1*PW2 + 128 + tid]          \
                     + part[2*PW2 + 128 + tid] + part[3*PW2 + 128 + tid];         \
            float an = part[0*PW2 + 256 + tid] + part[1*PW2 + 256 + tid]          \
                     + part[2*PW2 + 256 + tid] + part[3*PW2 + 256 + tid];         \
            int tp = t + 2; if (tp > T_DIM - 1) tp = T_DIM - 1;                   \
            const float* gp = gxb + (size_t)tp * G_DIM + tid;                     \
            float nxr = gp[0], nxz = gp[128], nxn = gp[256];                      \
            float r  = sigmoid_f(CXR + ar + bhr);                                 \
            float z  = sigmoid_f(CXZ + az + bhz);                                 \
            float nn = tanh_f(CXN + r * (an + bhn));                              \
            float hnew = nn + z * (h_prev - nn);                                  \
            h_prev = hnew;                                                        \
            ((_Float16*)&hbuf[PR ^ 1][0])[tid] = (_Float16)hnew;                  \
            if (WRITE_SEQ) seqb[(size_t)t * H_DIM + tid] = hnew;                  \
            CXR = nxr; CXZ = nxz; CXN = nxn;                                      \
        }                                                                         \
        __syncthreads();                                                          \
    }

template<bool WRITE_SEQ>
__global__ __attribute__((amdgpu_flat_work_group_size(512, 512),
                          amdgpu_waves_per_eu(2, 2)))
void gru_scan_mfma_kernel(const float* __restrict__ gx,    // [B,T,3H] (incl b_ih)
                          const float* __restrict__ whh,   // [3H,H] this layer
                          const float* __restrict__ bhh,   // [3H]
                          const int*   __restrict__ lengths,
                          float* __restrict__ seq_out,     // [B,T,H] if WRITE_SEQ
                          float* __restrict__ final_out)   // [B,H]  if !WRITE_SEQ
{
    __shared__ __align__(16) uint32 hbuf[2][72];     // 128 f16 + pad, dbuf
    __shared__ __align__(16) float  part[4 * PW2];   // [kc][j<384]

    const int b   = blockIdx.x;
    const int tid = threadIdx.x;
    const int w   = tid >> 6;        // wave 0..7
    const int ln  = tid & 63;
    const int kcIdx = w & 3;
    const int kc  = kcIdx * 32;
    const int j0  = (w >> 2) * 192;
    const int fr  = ln & 15;         // j within tile
    const int fq  = ln >> 4;         // k-subchunk 0..3

    // resident B-fragments: tile i -> rows j0+i*16+fr of W, k = kc+fq*8..+8
    f16x8 wF[12];
#pragma unroll
    for (int i = 0; i < 12; ++i) {
        const float* wp = whh + (size_t)(j0 + i * 16 + fr) * H_DIM + kc + fq * 8;
        float4 v0 = *(const float4*)wp;
        float4 v1 = *(const float4*)(wp + 4);
        u32x4 u;
        u.x = packf16(v0.x, v0.y); u.y = packf16(v0.z, v0.w);
        u.z = packf16(v1.x, v1.y); u.w = packf16(v1.z, v1.w);
        wF[i] = __builtin_bit_cast(f16x8, u);
    }

    const int len = lengths[b];
    const float* gxb = gx + (size_t)b * T_DIM * G_DIM;
    float* seqb = WRITE_SEQ ? (seq_out + (size_t)b * T_DIM * H_DIM) : nullptr;

    float bhr = 0.f, bhz = 0.f, bhn = 0.f;
    float exr = 0.f, exz = 0.f, exn = 0.f, oxr = 0.f, oxz = 0.f, oxn = 0.f;
    if (tid < H_DIM) {
        bhr = bhh[tid]; bhz = bhh[tid + 128]; bhn = bhh[tid + 256];
        exr = gxb[tid];         exz = gxb[tid + 128];         exn = gxb[tid + 256];
        oxr = gxb[G_DIM + tid]; oxz = gxb[G_DIM + tid + 128]; oxn = gxb[G_DIM + tid + 256];
    }

    for (int i = tid; i < 2 * 72; i += 512) ((uint32*)hbuf)[i] = 0u;
    __syncthreads();

    float h_prev = 0.0f;   // gate threads: fp32 master copy of h[tid]

    int t = 0;
    while (t < len) {      // len is block-uniform; barriers stay uniform
        SCAN_STEP(0, exr, exz, exn)
        ++t;
        if (t >= len) break;
        SCAN_STEP(1, oxr, oxz, oxn)
        ++t;
    }

    if (!WRITE_SEQ && tid < H_DIM)
        final_out[(size_t)b * H_DIM + tid] = h_prev;
}

extern "C" void kernel_launch(void* const* d_in, const int* in_sizes, int n_in,
                              void* d_out, int out_size, void* d_ws, size_t ws_size,
                              hipStream_t stream)
{
    (void)in_sizes; (void)n_in; (void)out_size; (void)ws_size;
    const float* x      = (const float*)d_in[0];
    const float* w_proj = (const float*)d_in[1];
    const float* b_proj = (const float*)d_in[2];
    const float* w_ih   = (const float*)d_in[3];
    const float* w_hh   = (const float*)d_in[4];
    const float* b_ih   = (const float*)d_in[5];
    const float* b_hh   = (const float*)d_in[6];
    float* out = (float*)d_out;

    char*  ws      = (char*)d_ws;
    float* feat    = (float*)(ws);
    float* gxbuf   = (float*)(ws + 67108864ull);
    int*   lengths = (int*)  (ws + 268435456ull);

    hipMemsetAsync(lengths, 0, B_DIM * sizeof(int), stream);

    // 1) feat = x @ w_proj^T + b_proj (+ lengths)   M=131072, N=128, K=512
    gemm_mfma_kernel<F_DIM, H_DIM, true>
        <<<dim3(1024, 1), 256, 0, stream>>>(x, w_proj, b_proj, feat, lengths);
    // 2) gx0 = feat @ w_ih[0]^T + b_ih[0]           N=384, K=128
    gemm_mfma_kernel<H_DIM, G_DIM, false>
        <<<dim3(1024, 3), 256, 0, stream>>>(feat, w_ih, b_ih, gxbuf, nullptr);
    // 3) layer-0 scan -> out0 (overwrites feat)
    gru_scan_mfma_kernel<true><<<B_DIM, 512, 0, stream>>>(
        gxbuf, w_hh, b_hh, lengths, feat, nullptr);
    // 4) gx1 = out0 @ w_ih[1]^T + b_ih[1]
    gemm_mfma_kernel<H_DIM, G_DIM, false>
        <<<dim3(1024, 3), 256, 0, stream>>>(feat, w_ih + G_DIM*H_DIM, b_ih + G_DIM, gxbuf, nullptr);
    // 5) layer-1 scan -> final top-layer state
    gru_scan_mfma_kernel<false><<<B_DIM, 512, 0, stream>>>(
        gxbuf, w_hh + G_DIM*H_DIM, b_hh + G_DIM, lengths, nullptr, out);
}

// Round 16
// 2778.008 us; speedup vs baseline: 1.7368x; 1.3195x over previous
//
#include <hip/hip_runtime.h>

#define B_DIM 64
#define T_DIM 2048
#define F_DIM 512
#define H_DIM 128
#define G_DIM 384  // 3*H

typedef _Float16 half2_t __attribute__((ext_vector_type(2)));
typedef _Float16 f16x8   __attribute__((ext_vector_type(8)));
typedef unsigned int uint32;
typedef uint32 u32x4 __attribute__((ext_vector_type(4)));
typedef short bf16x8 __attribute__((ext_vector_type(8)));
typedef float f32x4  __attribute__((ext_vector_type(4)));

__device__ __forceinline__ float sigmoid_f(float x) {
    return __fdividef(1.0f, 1.0f + __expf(-x));
}
__device__ __forceinline__ float tanh_f(float x) {
    return __fdividef(2.0f, 1.0f + __expf(-2.0f * x)) - 1.0f;
}

__device__ __forceinline__ uint32 packf16(float a, float b) {
    half2_t p; p.x = (_Float16)a; p.y = (_Float16)b;
    return __builtin_bit_cast(uint32, p);
}

__device__ __forceinline__ uint32 pk_bf16(float lo, float hi) {
    uint32 r;
    asm("v_cvt_pk_bf16_f32 %0, %1, %2" : "=v"(r) : "v"(lo), "v"(hi));
    return r;
}

// ---------------------------------------------------------------------------
// bf16 MFMA GEMM (R10-proven): C[M x NDIM] = A @ W^T + bias; optional lengths.
// ---------------------------------------------------------------------------
template<int KDIM, int NDIM, bool DO_LEN>
__global__ __launch_bounds__(256)
void gemm_mfma_kernel(const float* __restrict__ A, const float* __restrict__ W,
                      const float* __restrict__ bias, float* __restrict__ C,
                      int* __restrict__ lengths)
{
    constexpr int KSTEPS = KDIM / 32;
    constexpr int PAD = 40;
    __shared__ __align__(16) unsigned short At[128 * PAD];
    __shared__ __align__(16) unsigned short Bt[128 * PAD];

    const int tid = threadIdx.x;
    const int m0  = blockIdx.x * 128;
    const int n0  = blockIdx.y * 128;
    const int row = tid >> 1;
    const int kh  = tid & 1;

    const float* Ap = A + (size_t)(m0 + row) * KDIM + kh * 16;
    const float* Wp = W + (size_t)(n0 + row) * KDIM + kh * 16;

    float4 aPre[4], bPre[4];
#pragma unroll
    for (int q = 0; q < 4; ++q) {
        aPre[q] = *(const float4*)(Ap + q * 4);
        bPre[q] = *(const float4*)(Wp + q * 4);
    }

    f32x4 acc[4][4];
#pragma unroll
    for (int i = 0; i < 4; ++i)
#pragma unroll
        for (int j = 0; j < 4; ++j) acc[i][j] = (f32x4){0.f, 0.f, 0.f, 0.f};

    const int wv = tid >> 6;
    const int wm = (wv >> 1) * 64;
    const int wn = (wv & 1) * 64;
    const int ln = tid & 63;
    const int fr = ln & 15;
    const int fq = ln >> 4;

    float rowsum = 0.0f;

    for (int ks = 0; ks < KSTEPS; ++ks) {
        if (DO_LEN) {
#pragma unroll
            for (int q = 0; q < 4; ++q)
                rowsum += aPre[q].x + aPre[q].y + aPre[q].z + aPre[q].w;
        }
        {
            uint32* ad = (uint32*)&At[row * PAD + kh * 16];
            uint32* bd = (uint32*)&Bt[row * PAD + kh * 16];
            uint4 au, bu;
            au.x = pk_bf16(aPre[0].x, aPre[0].y); au.y = pk_bf16(aPre[0].z, aPre[0].w);
            au.z = pk_bf16(aPre[1].x, aPre[1].y); au.w = pk_bf16(aPre[1].z, aPre[1].w);
            *(uint4*)ad = au;
            au.x = pk_bf16(aPre[2].x, aPre[2].y); au.y = pk_bf16(aPre[2].z, aPre[2].w);
            au.z = pk_bf16(aPre[3].x, aPre[3].y); au.w = pk_bf16(aPre[3].z, aPre[3].w);
            *(uint4*)(ad + 4) = au;
            bu.x = pk_bf16(bPre[0].x, bPre[0].y); bu.y = pk_bf16(bPre[0].z, bPre[0].w);
            bu.z = pk_bf16(bPre[1].x, bPre[1].y); bu.w = pk_bf16(bPre[1].z, bPre[1].w);
            *(uint4*)bd = bu;
            bu.x = pk_bf16(bPre[2].x, bPre[2].y); bu.y = pk_bf16(bPre[2].z, bPre[2].w);
            bu.z = pk_bf16(bPre[3].x, bPre[3].y); bu.w = pk_bf16(bPre[3].z, bPre[3].w);
            *(uint4*)(bd + 4) = bu;
        }
        __syncthreads();
        if (ks + 1 < KSTEPS) {
#pragma unroll
            for (int q = 0; q < 4; ++q) {
                aPre[q] = *(const float4*)(Ap + (ks + 1) * 32 + q * 4);
                bPre[q] = *(const float4*)(Wp + (ks + 1) * 32 + q * 4);
            }
        }
        bf16x8 aF[4], bF[4];
#pragma unroll
        for (int i = 0; i < 4; ++i) {
            aF[i] = *(const bf16x8*)&At[(wm + i * 16 + fr) * PAD + fq * 8];
            bF[i] = *(const bf16x8*)&Bt[(wn + i * 16 + fr) * PAD + fq * 8];
        }
#pragma unroll
        for (int i = 0; i < 4; ++i)
#pragma unroll
            for (int j = 0; j < 4; ++j)
                acc[i][j] = __builtin_amdgcn_mfma_f32_16x16x32_bf16(
                                aF[i], bF[j], acc[i][j], 0, 0, 0);
        __syncthreads();
    }

#pragma unroll
    for (int i = 0; i < 4; ++i) {
#pragma unroll
        for (int j = 0; j < 4; ++j) {
            const int n = n0 + wn + j * 16 + fr;
            const float bn = bias[n];
            const int mbase = m0 + wm + i * 16 + fq * 4;
#pragma unroll
            for (int r = 0; r < 4; ++r)
                C[(size_t)(mbase + r) * NDIM + n] = acc[i][j][r] + bn;
        }
    }

    if (DO_LEN && blockIdx.y == 0) {
        rowsum += __shfl_xor(rowsum, 1);
        if (kh == 0 && rowsum != 0.0f)
            atomicAdd(&lengths[(m0 + row) >> 11], 1);
    }
}

// ---------------------------------------------------------------------------
// Barrier-minimal MFMA GRU scan. One block per batch element, 512 threads =
// 8 waves, waves_per_eu(2,2).
// Wave w FULLY owns j in [w*16, w*16+16): per gate g, a 4-deep chained
// mfma_f32_16x16x32_f16 over k-chunks c=0..3 (A = h broadcast: every logical
// A-row identical), so after 12 MFMAs every lane's acc[0] holds the COMPLETE
// K=128 dot for j = w*16 + (ln&15), gate g. No cross-lane reduce, no partial
// LDS round-trip, no separate gate phase: all lanes run gate math redundantly
// (fq replicas), fq==0 lanes write h' as f16 -> ONE barrier per step.
// Resident: 12 f16x8 = 48 u32 (the R8/R9/R15-proven resident count).
// h ds_reads: 4 distinct 16B slices/wave, 16-lane broadcast each -> no
// conflicts. h write: 16 lanes b16 consecutive (2-way, free).
// ---------------------------------------------------------------------------
#define SCAN_STEP(PR, CXR, CXZ, CXN)                                              \
    {                                                                             \
        const _Float16* hb = (const _Float16*)&hbuf[PR][0];                       \
        f16x8 ha0 = *(const f16x8*)(hb + 0 * 32 + fq * 8);                        \
        f16x8 ha1 = *(const f16x8*)(hb + 1 * 32 + fq * 8);                        \
        f16x8 ha2 = *(const f16x8*)(hb + 2 * 32 + fq * 8);                        \
        f16x8 ha3 = *(const f16x8*)(hb + 3 * 32 + fq * 8);                        \
        f32x4 accr = (f32x4){0.f,0.f,0.f,0.f};                                    \
        f32x4 accz = (f32x4){0.f,0.f,0.f,0.f};                                    \
        f32x4 accn = (f32x4){0.f,0.f,0.f,0.f};                                    \
        accr = __builtin_amdgcn_mfma_f32_16x16x32_f16(ha0, wR0, accr, 0, 0, 0);   \
        accz = __builtin_amdgcn_mfma_f32_16x16x32_f16(ha0, wZ0, accz, 0, 0, 0);   \
        accn = __builtin_amdgcn_mfma_f32_16x16x32_f16(ha0, wN0, accn, 0, 0, 0);   \
        accr = __builtin_amdgcn_mfma_f32_16x16x32_f16(ha1, wR1, accr, 0, 0, 0);   \
        accz = __builtin_amdgcn_mfma_f32_16x16x32_f16(ha1, wZ1, accz, 0, 0, 0);   \
        accn = __builtin_amdgcn_mfma_f32_16x16x32_f16(ha1, wN1, accn, 0, 0, 0);   \
        accr = __builtin_amdgcn_mfma_f32_16x16x32_f16(ha2, wR2, accr, 0, 0, 0);   \
        accz = __builtin_amdgcn_mfma_f32_16x16x32_f16(ha2, wZ2, accz, 0, 0, 0);   \
        accn = __builtin_amdgcn_mfma_f32_16x16x32_f16(ha2, wN2, accn, 0, 0, 0);   \
        accr = __builtin_amdgcn_mfma_f32_16x16x32_f16(ha3, wR3, accr, 0, 0, 0);   \
        accz = __builtin_amdgcn_mfma_f32_16x16x32_f16(ha3, wZ3, accz, 0, 0, 0);   \
        accn = __builtin_amdgcn_mfma_f32_16x16x32_f16(ha3, wN3, accn, 0, 0, 0);   \
        float ar = accr[0], az = accz[0], an = accn[0];                           \
        int tp = t + 2; if (tp > T_DIM - 1) tp = T_DIM - 1;                       \
        const float* gp = gxb + (size_t)tp * G_DIM + jl;                          \
        float nxr = gp[0], nxz = gp[128], nxn = gp[256];                          \
        float r  = sigmoid_f(CXR + ar + bhr);                                     \
        float z  = sigmoid_f(CXZ + az + bhz);                                     \
        float nn = tanh_f(CXN + r * (an + bhn));                                  \
        float hnew = nn + z * (h_prev - nn);                                      \
        h_prev = hnew;                                                            \
        if (fq == 0) {                                                            \
            ((_Float16*)&hbuf[PR ^ 1][0])[jl] = (_Float16)hnew;                   \
            if (WRITE_SEQ) seqb[(size_t)t * H_DIM + jl] = hnew;                   \
        }                                                                         \
        CXR = nxr; CXZ = nxz; CXN = nxn;                                          \
        __syncthreads();                                                          \
    }

template<bool WRITE_SEQ>
__global__ __attribute__((amdgpu_flat_work_group_size(512, 512),
                          amdgpu_waves_per_eu(2, 2)))
void gru_scan_mfma_kernel(const float* __restrict__ gx,    // [B,T,3H] (incl b_ih)
                          const float* __restrict__ whh,   // [3H,H] this layer
                          const float* __restrict__ bhh,   // [3H]
                          const int*   __restrict__ lengths,
                          float* __restrict__ seq_out,     // [B,T,H] if WRITE_SEQ
                          float* __restrict__ final_out)   // [B,H]  if !WRITE_SEQ
{
    __shared__ __align__(16) uint32 hbuf[2][68];    // 128 f16 + pad, dbuf

    const int b   = blockIdx.x;
    const int tid = threadIdx.x;
    const int w   = tid >> 6;        // wave 0..7 -> j block
    const int ln  = tid & 63;
    const int fr  = ln & 15;         // j within block
    const int fq  = ln >> 4;         // k-subchunk 0..3 (replica group)
    const int jl  = w * 16 + fr;     // this lane's output element

    // resident B-fragments: gate g, chunk c -> W_hh[g*128 + jl][c*32 + fq*8 ..+8]
    f16x8 wR0, wR1, wR2, wR3, wZ0, wZ1, wZ2, wZ3, wN0, wN1, wN2, wN3;
    {
        const float* base = whh + (size_t)jl * H_DIM + fq * 8;
#define LOADW(dst, g, c)                                                          \
        {                                                                         \
            const float* wp = base + (size_t)(g) * 128 * H_DIM + (c) * 32;        \
            float4 v0 = *(const float4*)wp;                                       \
            float4 v1 = *(const float4*)(wp + 4);                                 \
            u32x4 u;                                                              \
            u.x = packf16(v0.x, v0.y); u.y = packf16(v0.z, v0.w);                 \
            u.z = packf16(v1.x, v1.y); u.w = packf16(v1.z, v1.w);                 \
            dst = __builtin_bit_cast(f16x8, u);                                   \
        }
        LOADW(wR0, 0, 0) LOADW(wR1, 0, 1) LOADW(wR2, 0, 2) LOADW(wR3, 0, 3)
        LOADW(wZ0, 1, 0) LOADW(wZ1, 1, 1) LOADW(wZ2, 1, 2) LOADW(wZ3, 1, 3)
        LOADW(wN0, 2, 0) LOADW(wN1, 2, 1) LOADW(wN2, 2, 2) LOADW(wN3, 2, 3)
#undef LOADW
    }

    const int len = lengths[b];
    const float* gxb = gx + (size_t)b * T_DIM * G_DIM;
    float* seqb = WRITE_SEQ ? (seq_out + (size_t)b * T_DIM * H_DIM) : nullptr;

    const float bhr = bhh[jl], bhz = bhh[jl + 128], bhn = bhh[jl + 256];

    // gx ping-pong prefetch (2 steps ahead); fq replicas load redundantly
    float exr = gxb[jl],         exz = gxb[jl + 128],         exn = gxb[jl + 256];
    float oxr = gxb[G_DIM + jl], oxz = gxb[G_DIM + jl + 128], oxn = gxb[G_DIM + jl + 256];

    for (int i = tid; i < 2 * 68; i += 512) ((uint32*)hbuf)[i] = 0u;
    __syncthreads();

    float h_prev = 0.0f;   // fp32 master copy of h[jl], identical across fq

    int t = 0;
    while (t < len) {      // len is block-uniform; barriers stay uniform
        SCAN_STEP(0, exr, exz, exn)
        ++t;
        if (t >= len) break;
        SCAN_STEP(1, oxr, oxz, oxn)
        ++t;
    }

    if (!WRITE_SEQ && fq == 0)
        final_out[(size_t)b * H_DIM + jl] = h_prev;
}

extern "C" void kernel_launch(void* const* d_in, const int* in_sizes, int n_in,
                              void* d_out, int out_size, void* d_ws, size_t ws_size,
                              hipStream_t stream)
{
    (void)in_sizes; (void)n_in; (void)out_size; (void)ws_size;
    const float* x      = (const float*)d_in[0];
    const float* w_proj = (const float*)d_in[1];
    const float* b_proj = (const float*)d_in[2];
    const float* w_ih   = (const float*)d_in[3];
    const float* w_hh   = (const float*)d_in[4];
    const float* b_ih   = (const float*)d_in[5];
    const float* b_hh   = (const float*)d_in[6];
    float* out = (float*)d_out;

    char*  ws      = (char*)d_ws;
    float* feat    = (float*)(ws);
    float* gxbuf   = (float*)(ws + 67108864ull);
    int*   lengths = (int*)  (ws + 268435456ull);

    hipMemsetAsync(lengths, 0, B_DIM * sizeof(int), stream);

    // 1) feat = x @ w_proj^T + b_proj (+ lengths)   M=131072, N=128, K=512
    gemm_mfma_kernel<F_DIM, H_DIM, true>
        <<<dim3(1024, 1), 256, 0, stream>>>(x, w_proj, b_proj, feat, lengths);
    // 2) gx0 = feat @ w_ih[0]^T + b_ih[0]           N=384, K=128
    gemm_mfma_kernel<H_DIM, G_DIM, false>
        <<<dim3(1024, 3), 256, 0, stream>>>(feat, w_ih, b_ih, gxbuf, nullptr);
    // 3) layer-0 scan -> out0 (overwrites feat)
    gru_scan_mfma_kernel<true><<<B_DIM, 512, 0, stream>>>(
        gxbuf, w_hh, b_hh, lengths, feat, nullptr);
    // 4) gx1 = out0 @ w_ih[1]^T + b_ih[1]
    gemm_mfma_kernel<H_DIM, G_DIM, false>
        <<<dim3(1024, 3), 256, 0, stream>>>(feat, w_ih + G_DIM*H_DIM, b_ih + G_DIM, gxbuf, nullptr);
    // 5) layer-1 scan -> final top-layer state
    gru_scan_mfma_kernel<false><<<B_DIM, 512, 0, stream>>>(
        gxbuf, w_hh + G_DIM*H_DIM, b_hh + G_DIM, lengths, nullptr, out);
}

// Round 17
// 2776.412 us; speedup vs baseline: 1.7378x; 1.0006x over previous
//
#include <hip/hip_runtime.h>

#define B_DIM 64
#define T_DIM 2048
#define F_DIM 512
#define H_DIM 128
#define G_DIM 384  // 3*H

typedef _Float16 half2_t __attribute__((ext_vector_type(2)));
typedef _Float16 f16x8   __attribute__((ext_vector_type(8)));
typedef unsigned int uint32;
typedef uint32 u32x4 __attribute__((ext_vector_type(4)));
typedef short bf16x8 __attribute__((ext_vector_type(8)));
typedef float f32x4  __attribute__((ext_vector_type(4)));

__device__ __forceinline__ float sigmoid_f(float x) {
    return __fdividef(1.0f, 1.0f + __expf(-x));
}
__device__ __forceinline__ float tanh_f(float x) {
    return __fdividef(2.0f, 1.0f + __expf(-2.0f * x)) - 1.0f;
}

__device__ __forceinline__ uint32 packf16(float a, float b) {
    half2_t p; p.x = (_Float16)a; p.y = (_Float16)b;
    return __builtin_bit_cast(uint32, p);
}

__device__ __forceinline__ uint32 pk_bf16(float lo, float hi) {
    uint32 r;
    asm("v_cvt_pk_bf16_f32 %0, %1, %2" : "=v"(r) : "v"(lo), "v"(hi));
    return r;
}

// Minimal barrier: drain LDS only (lgkmcnt), leave global loads in flight
// across the barrier (T4: never vmcnt(0) in the recurrence loop). The scan's
// cross-wave communication is LDS-only, so this is sufficient; gx prefetch
// results are consumed 2 steps later (compiler inserts counted vmcnt at use).
// sched_barrier(0) on both sides pins DS ops against reordering (rule #18).
#define FAST_BARRIER()                                                            \
    __builtin_amdgcn_sched_barrier(0);                                            \
    asm volatile("s_waitcnt lgkmcnt(0)" ::: "memory");                            \
    __builtin_amdgcn_s_barrier();                                                 \
    __builtin_amdgcn_sched_barrier(0);

// ---------------------------------------------------------------------------
// bf16 MFMA GEMM (R10-proven): C[M x NDIM] = A @ W^T + bias; optional lengths.
// ---------------------------------------------------------------------------
template<int KDIM, int NDIM, bool DO_LEN>
__global__ __launch_bounds__(256)
void gemm_mfma_kernel(const float* __restrict__ A, const float* __restrict__ W,
                      const float* __restrict__ bias, float* __restrict__ C,
                      int* __restrict__ lengths)
{
    constexpr int KSTEPS = KDIM / 32;
    constexpr int PAD = 40;
    __shared__ __align__(16) unsigned short At[128 * PAD];
    __shared__ __align__(16) unsigned short Bt[128 * PAD];

    const int tid = threadIdx.x;
    const int m0  = blockIdx.x * 128;
    const int n0  = blockIdx.y * 128;
    const int row = tid >> 1;
    const int kh  = tid & 1;

    const float* Ap = A + (size_t)(m0 + row) * KDIM + kh * 16;
    const float* Wp = W + (size_t)(n0 + row) * KDIM + kh * 16;

    float4 aPre[4], bPre[4];
#pragma unroll
    for (int q = 0; q < 4; ++q) {
        aPre[q] = *(const float4*)(Ap + q * 4);
        bPre[q] = *(const float4*)(Wp + q * 4);
    }

    f32x4 acc[4][4];
#pragma unroll
    for (int i = 0; i < 4; ++i)
#pragma unroll
        for (int j = 0; j < 4; ++j) acc[i][j] = (f32x4){0.f, 0.f, 0.f, 0.f};

    const int wv = tid >> 6;
    const int wm = (wv >> 1) * 64;
    const int wn = (wv & 1) * 64;
    const int ln = tid & 63;
    const int fr = ln & 15;
    const int fq = ln >> 4;

    float rowsum = 0.0f;

    for (int ks = 0; ks < KSTEPS; ++ks) {
        if (DO_LEN) {
#pragma unroll
            for (int q = 0; q < 4; ++q)
                rowsum += aPre[q].x + aPre[q].y + aPre[q].z + aPre[q].w;
        }
        {
            uint32* ad = (uint32*)&At[row * PAD + kh * 16];
            uint32* bd = (uint32*)&Bt[row * PAD + kh * 16];
            uint4 au, bu;
            au.x = pk_bf16(aPre[0].x, aPre[0].y); au.y = pk_bf16(aPre[0].z, aPre[0].w);
            au.z = pk_bf16(aPre[1].x, aPre[1].y); au.w = pk_bf16(aPre[1].z, aPre[1].w);
            *(uint4*)ad = au;
            au.x = pk_bf16(aPre[2].x, aPre[2].y); au.y = pk_bf16(aPre[2].z, aPre[2].w);
            au.z = pk_bf16(aPre[3].x, aPre[3].y); au.w = pk_bf16(aPre[3].z, aPre[3].w);
            *(uint4*)(ad + 4) = au;
            bu.x = pk_bf16(bPre[0].x, bPre[0].y); bu.y = pk_bf16(bPre[0].z, bPre[0].w);
            bu.z = pk_bf16(bPre[1].x, bPre[1].y); bu.w = pk_bf16(bPre[1].z, bPre[1].w);
            *(uint4*)bd = bu;
            bu.x = pk_bf16(bPre[2].x, bPre[2].y); bu.y = pk_bf16(bPre[2].z, bPre[2].w);
            bu.z = pk_bf16(bPre[3].x, bPre[3].y); bu.w = pk_bf16(bPre[3].z, bPre[3].w);
            *(uint4*)(bd + 4) = bu;
        }
        __syncthreads();
        if (ks + 1 < KSTEPS) {
#pragma unroll
            for (int q = 0; q < 4; ++q) {
                aPre[q] = *(const float4*)(Ap + (ks + 1) * 32 + q * 4);
                bPre[q] = *(const float4*)(Wp + (ks + 1) * 32 + q * 4);
            }
        }
        bf16x8 aF[4], bF[4];
#pragma unroll
        for (int i = 0; i < 4; ++i) {
            aF[i] = *(const bf16x8*)&At[(wm + i * 16 + fr) * PAD + fq * 8];
            bF[i] = *(const bf16x8*)&Bt[(wn + i * 16 + fr) * PAD + fq * 8];
        }
#pragma unroll
        for (int i = 0; i < 4; ++i)
#pragma unroll
            for (int j = 0; j < 4; ++j)
                acc[i][j] = __builtin_amdgcn_mfma_f32_16x16x32_bf16(
                                aF[i], bF[j], acc[i][j], 0, 0, 0);
        __syncthreads();
    }

#pragma unroll
    for (int i = 0; i < 4; ++i) {
#pragma unroll
        for (int j = 0; j < 4; ++j) {
            const int n = n0 + wn + j * 16 + fr;
            const float bn = bias[n];
            const int mbase = m0 + wm + i * 16 + fq * 4;
#pragma unroll
            for (int r = 0; r < 4; ++r)
                C[(size_t)(mbase + r) * NDIM + n] = acc[i][j][r] + bn;
        }
    }

    if (DO_LEN && blockIdx.y == 0) {
        rowsum += __shfl_xor(rowsum, 1);
        if (kh == 0 && rowsum != 0.0f)
            atomicAdd(&lengths[(m0 + row) >> 11], 1);
    }
}

// ---------------------------------------------------------------------------
// Barrier-minimal MFMA GRU scan (R16-proven structure). One block per batch
// element, 512 threads = 8 waves. Wave w owns j in [w*16, w*16+16): 12 chained
// mfma_f32_16x16x32_f16 (A = h broadcast) give every lane the complete K=128
// dot for its (j, gate) in acc[0]. No cross-lane reduce, no partial LDS
// round-trip; redundant gate math across fq replicas; fq==0 writes h' f16.
// ONE minimal barrier per step (lgkmcnt-only drain — gx loads stay in flight).
// Resident: 12 f16x8 = 48 u32 (proven-resident count).
// ---------------------------------------------------------------------------
#define SCAN_STEP(PR, CXR, CXZ, CXN)                                              \
    {                                                                             \
        const _Float16* hb = (const _Float16*)&hbuf[PR][0];                       \
        f16x8 ha0 = *(const f16x8*)(hb + 0 * 32 + fq * 8);                        \
        f16x8 ha1 = *(const f16x8*)(hb + 1 * 32 + fq * 8);                        \
        f16x8 ha2 = *(const f16x8*)(hb + 2 * 32 + fq * 8);                        \
        f16x8 ha3 = *(const f16x8*)(hb + 3 * 32 + fq * 8);                        \
        f32x4 accr = (f32x4){0.f,0.f,0.f,0.f};                                    \
        f32x4 accz = (f32x4){0.f,0.f,0.f,0.f};                                    \
        f32x4 accn = (f32x4){0.f,0.f,0.f,0.f};                                    \
        accr = __builtin_amdgcn_mfma_f32_16x16x32_f16(ha0, wR0, accr, 0, 0, 0);   \
        accz = __builtin_amdgcn_mfma_f32_16x16x32_f16(ha0, wZ0, accz, 0, 0, 0);   \
        accn = __builtin_amdgcn_mfma_f32_16x16x32_f16(ha0, wN0, accn, 0, 0, 0);   \
        accr = __builtin_amdgcn_mfma_f32_16x16x32_f16(ha1, wR1, accr, 0, 0, 0);   \
        accz = __builtin_amdgcn_mfma_f32_16x16x32_f16(ha1, wZ1, accz, 0, 0, 0);   \
        accn = __builtin_amdgcn_mfma_f32_16x16x32_f16(ha1, wN1, accn, 0, 0, 0);   \
        accr = __builtin_amdgcn_mfma_f32_16x16x32_f16(ha2, wR2, accr, 0, 0, 0);   \
        accz = __builtin_amdgcn_mfma_f32_16x16x32_f16(ha2, wZ2, accz, 0, 0, 0);   \
        accn = __builtin_amdgcn_mfma_f32_16x16x32_f16(ha2, wN2, accn, 0, 0, 0);   \
        accr = __builtin_amdgcn_mfma_f32_16x16x32_f16(ha3, wR3, accr, 0, 0, 0);   \
        accz = __builtin_amdgcn_mfma_f32_16x16x32_f16(ha3, wZ3, accz, 0, 0, 0);   \
        accn = __builtin_amdgcn_mfma_f32_16x16x32_f16(ha3, wN3, accn, 0, 0, 0);   \
        float ar = accr[0], az = accz[0], an = accn[0];                           \
        int tp = t + 2; if (tp > T_DIM - 1) tp = T_DIM - 1;                       \
        const float* gp = gxb + (size_t)tp * G_DIM + jl;                          \
        float nxr = gp[0], nxz = gp[128], nxn = gp[256];                          \
        float r  = sigmoid_f(CXR + ar + bhr);                                     \
        float z  = sigmoid_f(CXZ + az + bhz);                                     \
        float nn = tanh_f(CXN + r * (an + bhn));                                  \
        float hnew = nn + z * (h_prev - nn);                                      \
        h_prev = hnew;                                                            \
        if (fq == 0) {                                                            \
            ((_Float16*)&hbuf[PR ^ 1][0])[jl] = (_Float16)hnew;                   \
            if (WRITE_SEQ) seqb[(size_t)t * H_DIM + jl] = hnew;                   \
        }                                                                         \
        CXR = nxr; CXZ = nxz; CXN = nxn;                                          \
        FAST_BARRIER()                                                            \
    }

template<bool WRITE_SEQ>
__global__ __attribute__((amdgpu_flat_work_group_size(512, 512),
                          amdgpu_waves_per_eu(2, 2)))
void gru_scan_mfma_kernel(const float* __restrict__ gx,    // [B,T,3H] (incl b_ih)
                          const float* __restrict__ whh,   // [3H,H] this layer
                          const float* __restrict__ bhh,   // [3H]
                          const int*   __restrict__ lengths,
                          float* __restrict__ seq_out,     // [B,T,H] if WRITE_SEQ
                          float* __restrict__ final_out)   // [B,H]  if !WRITE_SEQ
{
    __shared__ __align__(16) uint32 hbuf[2][68];    // 128 f16 + pad, dbuf

    const int b   = blockIdx.x;
    const int tid = threadIdx.x;
    const int w   = tid >> 6;        // wave 0..7 -> j block
    const int ln  = tid & 63;
    const int fr  = ln & 15;         // j within block
    const int fq  = ln >> 4;         // k-subchunk 0..3 (replica group)
    const int jl  = w * 16 + fr;     // this lane's output element

    // resident B-fragments: gate g, chunk c -> W_hh[g*128 + jl][c*32 + fq*8 ..+8]
    f16x8 wR0, wR1, wR2, wR3, wZ0, wZ1, wZ2, wZ3, wN0, wN1, wN2, wN3;
    {
        const float* base = whh + (size_t)jl * H_DIM + fq * 8;
#define LOADW(dst, g, c)                                                          \
        {                                                                         \
            const float* wp = base + (size_t)(g) * 128 * H_DIM + (c) * 32;        \
            float4 v0 = *(const float4*)wp;                                       \
            float4 v1 = *(const float4*)(wp + 4);                                 \
            u32x4 u;                                                              \
            u.x = packf16(v0.x, v0.y); u.y = packf16(v0.z, v0.w);                 \
            u.z = packf16(v1.x, v1.y); u.w = packf16(v1.z, v1.w);                 \
            dst = __builtin_bit_cast(f16x8, u);                                   \
        }
        LOADW(wR0, 0, 0) LOADW(wR1, 0, 1) LOADW(wR2, 0, 2) LOADW(wR3, 0, 3)
        LOADW(wZ0, 1, 0) LOADW(wZ1, 1, 1) LOADW(wZ2, 1, 2) LOADW(wZ3, 1, 3)
        LOADW(wN0, 2, 0) LOADW(wN1, 2, 1) LOADW(wN2, 2, 2) LOADW(wN3, 2, 3)
#undef LOADW
    }

    const int len = lengths[b];
    const float* gxb = gx + (size_t)b * T_DIM * G_DIM;
    float* seqb = WRITE_SEQ ? (seq_out + (size_t)b * T_DIM * H_DIM) : nullptr;

    const float bhr = bhh[jl], bhz = bhh[jl + 128], bhn = bhh[jl + 256];

    // gx ping-pong prefetch (2 steps ahead); fq replicas load redundantly
    float exr = gxb[jl],         exz = gxb[jl + 128],         exn = gxb[jl + 256];
    float oxr = gxb[G_DIM + jl], oxz = gxb[G_DIM + jl + 128], oxn = gxb[G_DIM + jl + 256];

    for (int i = tid; i < 2 * 68; i += 512) ((uint32*)hbuf)[i] = 0u;
    __syncthreads();

    float h_prev = 0.0f;   // fp32 master copy of h[jl], identical across fq

    int t = 0;
    while (t < len) {      // len is block-uniform; barriers stay uniform
        SCAN_STEP(0, exr, exz, exn)
        ++t;
        if (t >= len) break;
        SCAN_STEP(1, oxr, oxz, oxn)
        ++t;
    }

    if (!WRITE_SEQ && fq == 0)
        final_out[(size_t)b * H_DIM + jl] = h_prev;
}

extern "C" void kernel_launch(void* const* d_in, const int* in_sizes, int n_in,
                              void* d_out, int out_size, void* d_ws, size_t ws_size,
                              hipStream_t stream)
{
    (void)in_sizes; (void)n_in; (void)out_size; (void)ws_size;
    const float* x      = (const float*)d_in[0];
    const float* w_proj = (const float*)d_in[1];
    const float* b_proj = (const float*)d_in[2];
    const float* w_ih   = (const float*)d_in[3];
    const float* w_hh   = (const float*)d_in[4];
    const float* b_ih   = (const float*)d_in[5];
    const float* b_hh   = (const float*)d_in[6];
    float* out = (float*)d_out;

    char*  ws      = (char*)d_ws;
    float* feat    = (float*)(ws);
    float* gxbuf   = (float*)(ws + 67108864ull);
    int*   lengths = (int*)  (ws + 268435456ull);

    hipMemsetAsync(lengths, 0, B_DIM * sizeof(int), stream);

    // 1) feat = x @ w_proj^T + b_proj (+ lengths)   M=131072, N=128, K=512
    gemm_mfma_kernel<F_DIM, H_DIM, true>
        <<<dim3(1024, 1), 256, 0, stream>>>(x, w_proj, b_proj, feat, lengths);
    // 2) gx0 = feat @ w_ih[0]^T + b_ih[0]           N=384, K=128
    gemm_mfma_kernel<H_DIM, G_DIM, false>
        <<<dim3(1024, 3), 256, 0, stream>>>(feat, w_ih, b_ih, gxbuf, nullptr);
    // 3) layer-0 scan -> out0 (overwrites feat)
    gru_scan_mfma_kernel<true><<<B_DIM, 512, 0, stream>>>(
        gxbuf, w_hh, b_hh, lengths, feat, nullptr);
    // 4) gx1 = out0 @ w_ih[1]^T + b_ih[1]
    gemm_mfma_kernel<H_DIM, G_DIM, false>
        <<<dim3(1024, 3), 256, 0, stream>>>(feat, w_ih + G_DIM*H_DIM, b_ih + G_DIM, gxbuf, nullptr);
    // 5) layer-1 scan -> final top-layer state
    gru_scan_mfma_kernel<false><<<B_DIM, 512, 0, stream>>>(
        gxbuf, w_hh + G_DIM*H_DIM, b_hh + G_DIM, lengths, nullptr, out);
}